// Round 10
// baseline (77.339 us; speedup 1.0000x reference)
//
#include <hip/hip_runtime.h>
#include <math.h>
#include <stdint.h>

#define LOG2E  1.44269504088896340736f
#define LN2    0.69314718055994530942f
#define LOG2PI 1.8378770664093453f

#define NN 2048
#define DD 64

// Schraudolph constants (scale 2^16, window [2^23, 2^24), x in [-120, +8)):
//   y = x*2^16 + BIAS_F;  exp2(x) ~= as_float((bits(y) << 7) + KBIT)
//   sigma = 0.035 centered -> worst-case output err ~2.3 << 9.8 (r9: absmax 2.0)
#define BIAS_F 16252928.0f
#define KBIT   2205910303u
#define CLAMP_LO 8388608.0f   // y floor (x = -120)

__device__ __forceinline__ float fexp2(float x) { return __builtin_amdgcn_exp2f(x); }
__device__ __forceinline__ float flog2(float x) { return __builtin_amdgcn_logf(x); }

// ---------------------------------------------------------------------------
// K1: per-(j,d) factors. a*log2e = z2*p + z*q + r2 with
//   p = -0.5*exp(-lv)*log2e, q = -2*mean*p, r2 = mean^2*p -0.5*(lv+LOG2PI)*log2e
// Outputs:
//   pq3[j*64+d] = {p*2^16, q*2^16}   (K3, Schraudolph-scaled)
//   r2s[j*64+d] = r2*2^16 + BIAS_F   (K3)
//   pqT[d][j]   = {p, q}             (K2, unscaled, coalesced in j)
//   r[j]        = sum_d r2           (K2, unscaled)
// ---------------------------------------------------------------------------
__global__ __launch_bounds__(1024) void k1_precompute(
    const float* __restrict__ z_mean, const float* __restrict__ z_lv,
    float2* __restrict__ pq3, float* __restrict__ r2s,
    float2* __restrict__ pqT, float* __restrict__ r)
{
    __shared__ float aL[64][65], bL[64][65], cL[64][65];
    int tid  = threadIdx.x;
    int lane = tid & 63;     // d in compute phases, j in store phases
    int row  = tid >> 6;     // 0..15
    int jb   = blockIdx.x * 64;

    #pragma unroll
    for (int ppp = 0; ppp < 4; ++ppp) {
        int jl  = ppp * 16 + row;
        int idx = (jb + jl) * DD + lane;
        float mean = z_mean[idx], lv = z_lv[idx];
        float p   = -0.5f * fexp2(-lv * LOG2E) * LOG2E;
        float q   = -2.0f * mean * p;
        float c22 = -0.5f * (lv + LOG2PI) * LOG2E;
        float r2  = fmaf(mean * mean, p, c22);
        pq3[idx] = make_float2(p * 65536.0f, q * 65536.0f);
        r2s[idx] = fmaf(r2, 65536.0f, BIAS_F);
        aL[jl][lane] = p; bL[jl][lane] = q; cL[jl][lane] = r2;
    }
    __syncthreads();
    #pragma unroll
    for (int ppp = 0; ppp < 4; ++ppp) {
        int dd = ppp * 16 + row;
        pqT[(size_t)dd * NN + jb + lane] = make_float2(aL[lane][dd], bL[lane][dd]);
    }
    if (tid < 64) {
        float s = 0.0f;
        #pragma unroll
        for (int dd = 0; dd < 64; ++dd) s += cL[tid][dd];
        r[jb + tid] = s;
    }
}

// ---------------------------------------------------------------------------
// K3: sums[jsl][i][d] = sum_{j in 512-slice} exp2s(z2*p + z*q + r2)
// (Schraudolph, 5 full-rate VALU ops/elem). Manual 2-stage register
// pipeline: prefetch batch b+1 (8 loads) while computing batch b (320 cy)
// -> L2 latency hidden. Tail prefetch reads one batch past the slice; for
// the final rows this lands in the adjacent ws array (valid memory, unused).
// Block: 512 thr = 8 waves; i-tile 8; wave owns 64 j's; lane = d.
// Grid: 256 i-tiles x 4 j-slices = 1024 blocks = 4/CU (100% occupancy).
// ---------------------------------------------------------------------------
__global__ __launch_bounds__(512) void k3_perd(
    const float* __restrict__ z, const float2* __restrict__ pq3,
    const float* __restrict__ r2s, float* __restrict__ sums)
{
    __shared__ float sm[8][8][DD];   // 16 KB
    int tid  = threadIdx.x;
    int lane = tid & 63, w = tid >> 6;   // 8 waves
    int it   = blockIdx.x >> 2;
    int jsl  = blockIdx.x & 3;
    int i0   = it * 8;
    int j0   = jsl * 512 + w * 64;

    float zr[8], z2r[8], s[8];
    #pragma unroll
    for (int k = 0; k < 8; ++k) {
        zr[k]  = z[(i0 + k) * DD + lane];
        z2r[k] = zr[k] * zr[k];
        s[k]   = 0.0f;
    }

    const float2* pp = pq3 + (size_t)j0 * DD + lane;
    const float*  rr = r2s + (size_t)j0 * DD + lane;

    float2 ca[4], cb[4];
    float  ra[4], rb[4];

#define PREF(C, R, B) {                                                      \
    const float2* p_ = pp + (size_t)(B) * 4 * DD;                            \
    const float*  q_ = rr + (size_t)(B) * 4 * DD;                            \
    _Pragma("unroll")                                                        \
    for (int u = 0; u < 4; ++u) { C[u] = p_[u * DD]; R[u] = q_[u * DD]; } }
#define COMP(C, R) {                                                         \
    _Pragma("unroll")                                                        \
    for (int u = 0; u < 4; ++u) {                                            \
        _Pragma("unroll")                                                    \
        for (int k = 0; k < 8; ++k) {                                        \
            float t = fmaf(z2r[k], C[u].x, fmaf(zr[k], C[u].y, R[u]));       \
            t = fmaxf(t, CLAMP_LO);                                          \
            s[k] += __uint_as_float((__float_as_uint(t) << 7) + KBIT);       \
        } } }

    PREF(ca, ra, 0);
    for (int b = 0; b < 16; b += 2) {
        PREF(cb, rb, b + 1);
        COMP(ca, ra);
        PREF(ca, ra, b + 2);   // b+2==16 on last iter: junk, valid mem, unused
        COMP(cb, rb);
    }
#undef PREF
#undef COMP

    #pragma unroll
    for (int k = 0; k < 8; ++k) sm[k][w][lane] = s[k];
    __syncthreads();

    // wave w finishes row i0+w
    float tot = 0.0f;
    #pragma unroll
    for (int w2 = 0; w2 < 8; ++w2) tot += sm[w][w2][lane];
    sums[((size_t)jsl * NN + i0 + w) * DD + lane] = tot;
}

// ---------------------------------------------------------------------------
// K2: acc[i][u] = sum_d z2*p + z*q for 4 j's per thread (j-tile 4 drops the
// ds:fma instruction ratio to 1:16, below the ~1:12 per-CU balance point).
// zz staged once in LDS (computed from z), broadcast float4 reads; pq read
// as 2 x b128; both ping-pong prefetched (pq 2 d-steps ahead for L2
// latency). Fixed-max epilogue: part = sum_j 2^{acc + r[j] + 64}.
// Block: 256 thr; i-tile 8; j-span 1024. Grid: 256 i-tiles x 2 = 512.
// ---------------------------------------------------------------------------
__global__ __launch_bounds__(256) void k2_logqz(
    const float* __restrict__ z, const float2* __restrict__ pqT,
    const float* __restrict__ r, float* __restrict__ k2part)
{
    __shared__ float2 zzL[DD][9];    // 4.6 KB, padded
    __shared__ float  red[8][256];   // 8 KB
    int tid = threadIdx.x;
    int it  = blockIdx.x >> 1;
    int jb  = blockIdx.x & 1;
    int i0  = it * 8;
    int j   = jb * 1024 + tid * 4;

    #pragma unroll
    for (int t2 = 0; t2 < 2; ++t2) {
        int idx = t2 * 256 + tid;    // 8 i x 64 d
        int i = idx >> 6, d = idx & 63;
        float zv = z[(i0 + i) * DD + d];
        zzL[d][i] = make_float2(zv * zv, zv);
    }
    __syncthreads();

    float acc[8][4];
    #pragma unroll
    for (int i = 0; i < 8; ++i)
        #pragma unroll
        for (int u = 0; u < 4; ++u) acc[i][u] = 0.0f;

    float4 za[4], zb[4];
    float4 p0a, p1a, p0b, p1b;

#define LDZ(Z, DI) {                                                         \
    int d_ = (DI) & 63;                                                      \
    _Pragma("unroll")                                                        \
    for (int q2 = 0; q2 < 4; ++q2)                                           \
        Z[q2] = *(const float4*)&zzL[d_][2 * q2]; }
#define LDP(P0, P1, DI) {                                                    \
    int d_ = (DI) & 63;                                                      \
    const float4* pq4 = (const float4*)(pqT + (size_t)d_ * NN + j);          \
    P0 = pq4[0]; P1 = pq4[1]; }
#define CMP(Z, P0, P1) {                                                     \
    _Pragma("unroll")                                                        \
    for (int i = 0; i < 8; ++i) {                                            \
        float z2v = (i & 1) ? Z[i >> 1].z : Z[i >> 1].x;                     \
        float zv  = (i & 1) ? Z[i >> 1].w : Z[i >> 1].y;                     \
        acc[i][0] = fmaf(z2v, P0.x, fmaf(zv, P0.y, acc[i][0]));              \
        acc[i][1] = fmaf(z2v, P0.z, fmaf(zv, P0.w, acc[i][1]));              \
        acc[i][2] = fmaf(z2v, P1.x, fmaf(zv, P1.y, acc[i][2]));              \
        acc[i][3] = fmaf(z2v, P1.z, fmaf(zv, P1.w, acc[i][3]));              \
    } }

    LDZ(za, 0);
    LDP(p0a, p1a, 0);
    LDP(p0b, p1b, 1);
    for (int d = 0; d < 64; d += 2) {
        LDZ(zb, d + 1);
        CMP(za, p0a, p1a);       // step d
        LDP(p0a, p1a, d + 2);    // 2-deep VMEM prefetch (wraps at end, unused)
        LDZ(za, d + 2);
        CMP(zb, p0b, p1b);       // step d+1
        LDP(p0b, p1b, d + 3);
    }
#undef LDZ
#undef LDP
#undef CMP

    float4 r4 = *(const float4*)(r + j);
    float ex[8];
    #pragma unroll
    for (int i = 0; i < 8; ++i) {
        ex[i] = fexp2(acc[i][0] + r4.x + 64.0f)
              + fexp2(acc[i][1] + r4.y + 64.0f)
              + fexp2(acc[i][2] + r4.z + 64.0f)
              + fexp2(acc[i][3] + r4.w + 64.0f);
    }
    #pragma unroll
    for (int i = 0; i < 8; ++i) red[i][tid] = ex[i];
    __syncthreads();

    int w = tid >> 6, lane = tid & 63;
    #pragma unroll
    for (int ii = w; ii < 8; ii += 4) {
        float ss = red[ii][lane] + red[ii][lane + 64]
                 + red[ii][lane + 128] + red[ii][lane + 192];
        #pragma unroll
        for (int off = 32; off; off >>= 1) ss += __shfl_xor(ss, off, 64);
        if (lane == 0) k2part[(size_t)jb * NN + i0 + ii] = ss;
    }
}

// ---------------------------------------------------------------------------
// K5: diff[i] = ln2*sum_d log2(sum_{4 jsl} sums) - ln2*(log2(sum_{2} part)-64)
// Block 256 = 4 i's (wave per i, lane = d). Grid 512.
// ---------------------------------------------------------------------------
__global__ __launch_bounds__(256) void k5_merge(
    const float* __restrict__ sums, const float* __restrict__ k2part,
    float* __restrict__ diff)
{
    int lane = threadIdx.x & 63, w = threadIdx.x >> 6;
    int i = blockIdx.x * 4 + w;

    float tot = 0.0f;
    #pragma unroll
    for (int q = 0; q < 4; ++q) tot += sums[((size_t)q * NN + i) * DD + lane];
    float t = flog2(tot);
    #pragma unroll
    for (int off = 32; off; off >>= 1) t += __shfl_xor(t, off, 64);

    if (lane == 0) {
        float ss = k2part[i] + k2part[NN + i];
        diff[i] = LN2 * t - LN2 * (flog2(ss) - 64.0f);
    }
}

// ---------------------------------------------------------------------------
// K6: out = mean_i diff[i]
// ---------------------------------------------------------------------------
__global__ __launch_bounds__(256) void k6_final(
    const float* __restrict__ diff, float* __restrict__ out)
{
    __shared__ float red[256];
    int tid = threadIdx.x;
    float t = 0.0f;
    for (int k = tid; k < NN; k += 256) t += diff[k];
    red[tid] = t;
    __syncthreads();
    #pragma unroll
    for (int off = 128; off; off >>= 1) {
        if (tid < off) red[tid] += red[tid + off];
        __syncthreads();
    }
    if (tid == 0) out[0] = red[0] * (1.0f / (float)NN);
}

extern "C" void kernel_launch(void* const* d_in, const int* in_sizes, int n_in,
                              void* d_out, int out_size, void* d_ws, size_t ws_size,
                              hipStream_t stream)
{
    const float* z      = (const float*)d_in[0];
    const float* z_mean = (const float*)d_in[1];
    const float* z_lv   = (const float*)d_in[2];
    float* out = (float*)d_out;

    float* ws = (float*)d_ws;
    float2* pq3    = (float2*)ws;                        // N*D f2  (1 MB)
    float*  r2s    = ws + (size_t)NN * DD * 2;           // N*D     (0.5 MB)
    float2* pqT    = (float2*)(ws + (size_t)NN * DD * 3);// N*D f2  (1 MB)
    float*  r      = ws + (size_t)NN * DD * 5;           // N
    float*  sums   = r + NN;                             // 4*N*D   (2 MB)
    float*  k2part = sums + (size_t)4 * NN * DD;         // 2*N
    float*  diff   = k2part + (size_t)2 * NN;            // N

    k1_precompute<<<NN / 64, 1024, 0, stream>>>(z_mean, z_lv, pq3, r2s, pqT, r);
    k3_perd<<<1024, 512, 0, stream>>>(z, pq3, r2s, sums);
    k2_logqz<<<512, 256, 0, stream>>>(z, pqT, r, k2part);
    k5_merge<<<NN / 4, 256, 0, stream>>>(sums, k2part, diff);
    k6_final<<<1, 256, 0, stream>>>(diff, out);
}